// Round 7
// baseline (242.117 us; speedup 1.0000x reference)
//
#include <hip/hip_runtime.h>
#include <math.h>

#define B_DIM 256
#define T_DIM 8192
#define BLOCK 256
#define RB_BLOCKS 6144                       // robot: 6144 blocks * 1024 f4 = 6,291,456 = B*T*3
#define PH_BLOCKS 1536                       // phase: 1536 blocks * 1024 f4 = 1,572,864 = B*T*3/4
#define GRID_BLOCKS (RB_BLOCKS + PH_BLOCKS)
#define NSLOT 256
#define N4_ROBOT (B_DIM * T_DIM * 3)         // 6291456 float4s
#define N4_PHASE (B_DIM * T_DIM * 3 / 4)     // 1572864 float4s
#define BF4_ROBOT (T_DIM * 3)                // 24576 f4 per batch (24 blocks/batch)

// ws: NSLOT slots x 8 doubles; 0 sse, 1 nll, 2 csum, 3 ccnt, 4 pen2, 5 velsq, 6 accsq

__global__ __launch_bounds__(BLOCK) void combined_loss_main(
    const float4* __restrict__ pred4,
    const float*  __restrict__ pred_phase,
    const float4* __restrict__ gt4,
    const int*    __restrict__ gt_phase,
    double* __restrict__ ws)
{
    __shared__ float s_red[4][8];
    const int tid = threadIdx.x;
    const int bx  = (int)blockIdx.x;

    float sse=0.f, nll=0.f, csum=0.f, ccnt=0.f, pen2=0.f, velsq=0.f, accsq=0.f;

    if (bx < RB_BLOCKS) {
        // -------- robot stream: thread owns 4 consecutive f4s; 14 batched loads --------
        const int J0 = bx * 1024 + tid * 4;              // global f4 index of first owned f4
        const int j0 = (bx % 24) * 1024 + tid * 4;       // within-batch f4 index

        float4 A[10];
        #pragma unroll
        for (int k = 0; k < 10; ++k) A[k] = pred4[min(J0 + k, N4_ROBOT - 1)];
        float4 G[4];
        #pragma unroll
        for (int k = 0; k < 4; ++k) G[k] = gt4[J0 + k];  // J0+3 <= N4-1 always

        #pragma unroll
        for (int i = 0; i < 4; ++i) {
            const float4 p0 = A[i], p3 = A[i+3], p6 = A[i+6], g = G[i];
            const float4 p1 = A[i+1], p4 = A[i+4];
            const int j = j0 + i;

            // sse (pointwise, flat-exact)
            float d;
            d = p0.x - g.x; sse += d*d;  d = p0.y - g.y; sse += d*d;
            d = p0.z - g.z; sse += d*d;  d = p0.w - g.w; sse += d*d;

            const bool vv = j < (BF4_ROBOT - 3);   // vel/speed valid
            const bool va = j < (BF4_ROBOT - 6);   // acc valid

            const float vx = p3.x - p0.x, vy = p3.y - p0.y;
            const float vz = p3.z - p0.z, vw = p3.w - p0.w;
            if (vv) velsq += vx*vx + vy*vy + vz*vz + vw*vw;

            if (va) {
                const float ax = p6.x - 2.f*p3.x + p0.x;
                const float ay = p6.y - 2.f*p3.y + p0.y;
                const float az = p6.z - 2.f*p3.z + p0.z;
                const float aw = p6.w - 2.f*p3.w + p0.w;
                accsq += ax*ax + ay*ay + az*az + aw*aw;
            }

            // speed: point ownership by j%3 (2/1/1 points), needs vel4(j) and vel4(j+1).xy
            const float wx = p4.x - p1.x, wy = p4.y - p1.y;
            const int s3 = j % 3;
            const float c0x = (s3 == 0) ? vx : ((s3 == 1) ? vz : vy);
            const float c0y = (s3 == 0) ? vy : ((s3 == 1) ? vw : vz);
            const float c0z = (s3 == 0) ? vz : ((s3 == 1) ? wx : vw);
            if (vv) {
                const float sp0 = sqrtf(c0x*c0x + c0y*c0y + c0z*c0z);
                const float d0 = sp0 - 10.f;
                if (d0 > 0.f) pen2 += d0*d0;
                if (s3 == 0) {
                    const float sp1 = sqrtf(vw*vw + wx*wx + wy*wy);
                    const float d1 = sp1 - 10.f;
                    if (d1 > 0.f) pen2 += d1*d1;
                }
            }
        }
    } else {
        // -------- phase stream: thread owns 4 consecutive f4s; batched loads --------
        const int pb    = bx - RB_BLOCKS;
        const int batch = pb / 6;
        const int M0    = pb * 1024 + tid * 4;
        const int m0    = (pb % 6) * 1024 + tid * 4;
        const int bT    = batch * T_DIM;
        const float4* ph4 = (const float4*)pred_phase;

        float4 A[6];
        #pragma unroll
        for (int k = 0; k < 6; ++k) A[k] = ph4[min(M0 + k, N4_PHASE - 1)];

        int qi[4], si[4], rA[4], gA[4], gB[4];
        #pragma unroll
        for (int i = 0; i < 4; ++i) {
            const int m = m0 + i;
            qi[i] = m / 3;
            si[i] = m - 3 * qi[i];
            rA[i] = 4*qi[i] + ((si[i] == 0) ? 0 : ((si[i] == 1) ? 2 : 3));
            gA[i] = gt_phase[bT + rA[i]];
            gB[i] = gt_phase[bT + 4*qi[i] + 1];
        }

        #pragma unroll
        for (int i = 0; i < 4; ++i) {
            const float4 v = A[i], nv = A[i+1], nn = A[i+2];
            const int s = si[i];

            const float la0 = (s == 0) ? v.x  : ((s == 1) ? v.z  : v.y);
            const float la1 = (s == 0) ? v.y  : ((s == 1) ? v.w  : v.z);
            const float la2 = (s == 0) ? v.z  : ((s == 1) ? nv.x : v.w);
            const float na0 = (s == 0) ? v.w  : ((s == 1) ? nv.y : nv.x);
            const float na1 = (s == 0) ? nv.x : ((s == 1) ? nv.z : nv.y);
            const float na2 = (s == 0) ? nv.y : ((s == 1) ? nv.w : nv.z);

            {
                const float mx  = fmaxf(la0, fmaxf(la1, la2));
                const float lse = mx + logf(expf(la0-mx) + expf(la1-mx) + expf(la2-mx));
                const float sl  = (gA[i] == 0) ? la0 : ((gA[i] == 1) ? la1 : la2);
                nll += lse - sl;
            }
            if (rA[i] < T_DIM - 1) {
                int p = 0; float pm = la0;
                if (la1 > pm) { pm = la1; p = 1; }
                if (la2 > pm) { pm = la2; p = 2; }
                int p1 = 0; float m1 = na0;
                if (na1 > m1) { m1 = na1; p1 = 1; }
                if (na2 > m1) { m1 = na2; p1 = 2; }
                const int mask = (p == 0) ? 4 : ((p == 1) ? 1 : 3);
                if ((mask >> p1) & 1) { csum += m1*m1; ccnt += 1.f; }
            }

            // Row B (s==0 threads only): rB = 4q+1
            if (s == 0) {
                const float lb0 = v.w,  lb1 = nv.x, lb2 = nv.y;
                const float nb0 = nv.z, nb1 = nv.w, nb2 = nn.x;
                const float mx  = fmaxf(lb0, fmaxf(lb1, lb2));
                const float lse = mx + logf(expf(lb0-mx) + expf(lb1-mx) + expf(lb2-mx));
                const float sl  = (gB[i] == 0) ? lb0 : ((gB[i] == 1) ? lb1 : lb2);
                nll += lse - sl;
                int p = 0; float pm = lb0;
                if (lb1 > pm) { pm = lb1; p = 1; }
                if (lb2 > pm) { pm = lb2; p = 2; }
                int p1 = 0; float m1 = nb0;
                if (nb1 > m1) { m1 = nb1; p1 = 1; }
                if (nb2 > m1) { m1 = nb2; p1 = 2; }
                const int mask = (p == 0) ? 4 : ((p == 1) ? 1 : 3);
                if ((mask >> p1) & 1) { csum += m1*m1; ccnt += 1.f; }
            }
        }
    }

    // ---- wave shuffle reduce -> one barrier -> slotted fp64 atomics ----
    float vals[7] = { sse, nll, csum, ccnt, pen2, velsq, accsq };
    #pragma unroll
    for (int off = 32; off > 0; off >>= 1) {
        #pragma unroll
        for (int q = 0; q < 7; ++q)
            vals[q] += __shfl_down(vals[q], off, 64);
    }
    const int wave = tid >> 6, lane = tid & 63;
    if (lane == 0) {
        #pragma unroll
        for (int q = 0; q < 7; ++q) s_red[wave][q] = vals[q];
    }
    __syncthreads();
    if (tid < 7) {
        double acc = (double)s_red[0][tid] + (double)s_red[1][tid]
                   + (double)s_red[2][tid] + (double)s_red[3][tid];
        atomicAdd(&ws[(size_t)(bx & (NSLOT - 1)) * 8 + tid], acc);
    }
}

__global__ __launch_bounds__(256) void combined_loss_final(
    const double* __restrict__ ws, float* __restrict__ out)
{
    __shared__ double sred[4][7];
    const int tid = threadIdx.x;
    double v[7];
    #pragma unroll
    for (int q = 0; q < 7; ++q) v[q] = ws[(size_t)tid * 8 + q];
    #pragma unroll
    for (int off = 32; off > 0; off >>= 1) {
        #pragma unroll
        for (int q = 0; q < 7; ++q)
            v[q] += __shfl_down(v[q], off, 64);
    }
    const int wave = tid >> 6, lane = tid & 63;
    if (lane == 0) {
        #pragma unroll
        for (int q = 0; q < 7; ++q) sred[wave][q] = v[q];
    }
    __syncthreads();
    if (tid == 0) {
        double s[7];
        #pragma unroll
        for (int q = 0; q < 7; ++q)
            s[q] = sred[0][q] + sred[1][q] + sred[2][q] + sred[3][q];
        const double robot = s[0] / (double)((size_t)B_DIM * T_DIM * 12);
        const double phase = s[1] / (double)((size_t)B_DIM * T_DIM);
        const double coher = (s[3] > 0.0) ? (s[2] / fmax(s[3], 1.0)) : 0.0;
        const double speed = 5.0  * (s[4] / (double)((size_t)B_DIM * (T_DIM - 1) * 4));
        const double vel   = 0.05 * (s[5] / (double)((size_t)B_DIM * (T_DIM - 1) * 12));
        const double acc   = 0.01 * (s[6] / (double)((size_t)B_DIM * (T_DIM - 2) * 12));
        out[0] = (float)(robot + phase + 10.0 * coher + speed + vel + acc);
    }
}

extern "C" void kernel_launch(void* const* d_in, const int* in_sizes, int n_in,
                              void* d_out, int out_size, void* d_ws, size_t ws_size,
                              hipStream_t stream)
{
    const float4* pred4      = (const float4*)d_in[0];
    const float*  pred_phase = (const float*)d_in[1];
    const float4* gt4        = (const float4*)d_in[2];
    const int*    gt_phase   = (const int*)d_in[3];
    double* ws  = (double*)d_ws;
    float*  out = (float*)d_out;

    hipMemsetAsync(d_ws, 0, (size_t)NSLOT * 8 * sizeof(double), stream);

    combined_loss_main<<<dim3(GRID_BLOCKS), BLOCK, 0, stream>>>(pred4, pred_phase, gt4, gt_phase, ws);
    combined_loss_final<<<1, 256, 0, stream>>>(ws, out);
}